// Round 1
// baseline (879.746 us; speedup 1.0000x reference)
//
#include <hip/hip_runtime.h>

#define CH 128

// ---------------------------------------------------------------------------
// deg[dst] += 1 per edge
__global__ __launch_bounds__(256) void deg_kernel(const int* __restrict__ dst,
                                                  float* __restrict__ deg, int E) {
    int e = blockIdx.x * 256 + threadIdx.x;
    if (e < E) atomicAdd(&deg[dst[e]], 1.0f);
}

// ---------------------------------------------------------------------------
// agg[dst, c] += feat[src, c]  — one thread per (edge, channel)
__global__ __launch_bounds__(256) void scatter_kernel(const float* __restrict__ feat,
                                                      const int* __restrict__ src,
                                                      const int* __restrict__ dst,
                                                      float* __restrict__ agg, int E) {
    int idx = blockIdx.x * 256 + threadIdx.x;   // E*128 = 81.92M < 2^31
    int e = idx >> 7;
    int c = idx & 127;
    if (e < E) {
        int s = src[e];   // same addr across half-wave -> broadcast load
        int d = dst[e];
        atomicAdd(&agg[d * CH + c], feat[s * CH + c]);
    }
}

// ---------------------------------------------------------------------------
// MODE 0:  C = relu( (A1 * invdeg) @ Wl + bias + A2 @ Wr )
// MODE 1:  C = alpha * (A1 @ Wl + bias) + (1-alpha) * A2
// Block: 256 threads, 32 rows. K = 128 staged fully in LDS.
template <int MODE>
__global__ __launch_bounds__(256) void gemm_kernel(
    const float* __restrict__ A1, const float* __restrict__ A2,
    const float* __restrict__ deg,
    const float* __restrict__ Wl, const float* __restrict__ Wr,
    const float* __restrict__ bias, const float* __restrict__ alpha_p,
    float* __restrict__ C, int n) {
    __shared__ float sA1[32][CH];
    __shared__ float sA2[32][CH];

    const int tid = threadIdx.x;
    const int rowBase = blockIdx.x * 32;

    // --- stage A1 (deg-normalized in MODE 0) and A2 tiles, float4 coalesced ---
#pragma unroll
    for (int t = 0; t < 4; ++t) {
        int i  = tid + t * 256;        // 0..1023
        int r  = i >> 5;               // 0..31
        int c4 = (i & 31) << 2;        // 0..124
        int gr = rowBase + r;
        float4 v1 = make_float4(0.f, 0.f, 0.f, 0.f);
        float4 v2 = v1;
        if (gr < n) {
            v1 = *(const float4*)&A1[gr * CH + c4];
            v2 = *(const float4*)&A2[gr * CH + c4];
            if (MODE == 0) {
                float inv = 1.0f / fmaxf(deg[gr], 1.0f);
                v1.x *= inv; v1.y *= inv; v1.z *= inv; v1.w *= inv;
            }
        }
        *(float4*)&sA1[r][c4] = v1;
        *(float4*)&sA2[r][c4] = v2;
    }
    __syncthreads();

    const int j4 = (tid & 31) << 2;    // output cols j4..j4+3
    const int r0 = (tid >> 5) << 2;    // output rows r0..r0+3 (within tile)

    float4 b4 = *(const float4*)&bias[j4];
    float4 acc[4];
#pragma unroll
    for (int r = 0; r < 4; ++r) acc[r] = b4;

    for (int k4 = 0; k4 < CH; k4 += 4) {
        float4 wl0 = *(const float4*)&Wl[(k4 + 0) * CH + j4];
        float4 wl1 = *(const float4*)&Wl[(k4 + 1) * CH + j4];
        float4 wl2 = *(const float4*)&Wl[(k4 + 2) * CH + j4];
        float4 wl3 = *(const float4*)&Wl[(k4 + 3) * CH + j4];
#pragma unroll
        for (int r = 0; r < 4; ++r) {
            float4 a1 = *(const float4*)&sA1[r0 + r][k4];   // broadcast read
            acc[r].x += a1.x * wl0.x + a1.y * wl1.x + a1.z * wl2.x + a1.w * wl3.x;
            acc[r].y += a1.x * wl0.y + a1.y * wl1.y + a1.z * wl2.y + a1.w * wl3.y;
            acc[r].z += a1.x * wl0.z + a1.y * wl1.z + a1.z * wl2.z + a1.w * wl3.z;
            acc[r].w += a1.x * wl0.w + a1.y * wl1.w + a1.z * wl2.w + a1.w * wl3.w;
        }
        if (MODE == 0) {
            float4 wr0 = *(const float4*)&Wr[(k4 + 0) * CH + j4];
            float4 wr1 = *(const float4*)&Wr[(k4 + 1) * CH + j4];
            float4 wr2 = *(const float4*)&Wr[(k4 + 2) * CH + j4];
            float4 wr3 = *(const float4*)&Wr[(k4 + 3) * CH + j4];
#pragma unroll
            for (int r = 0; r < 4; ++r) {
                float4 a2 = *(const float4*)&sA2[r0 + r][k4];
                acc[r].x += a2.x * wr0.x + a2.y * wr1.x + a2.z * wr2.x + a2.w * wr3.x;
                acc[r].y += a2.x * wr0.y + a2.y * wr1.y + a2.z * wr2.y + a2.w * wr3.y;
                acc[r].z += a2.x * wr0.z + a2.y * wr1.z + a2.z * wr2.z + a2.w * wr3.z;
                acc[r].w += a2.x * wr0.w + a2.y * wr1.w + a2.z * wr2.w + a2.w * wr3.w;
            }
        }
    }

    float alpha = 0.f, beta = 0.f;
    if (MODE == 1) { alpha = alpha_p[0]; beta = 1.0f - alpha; }

#pragma unroll
    for (int r = 0; r < 4; ++r) {
        int gr = rowBase + r0 + r;
        if (gr >= n) continue;
        float4 o = acc[r];
        if (MODE == 0) {
            o.x = fmaxf(o.x, 0.f); o.y = fmaxf(o.y, 0.f);
            o.z = fmaxf(o.z, 0.f); o.w = fmaxf(o.w, 0.f);
        } else {
            // residual blend with x (staged in sA2)
            o.x = alpha * o.x + beta * sA2[r0 + r][j4 + 0];
            o.y = alpha * o.y + beta * sA2[r0 + r][j4 + 1];
            o.z = alpha * o.z + beta * sA2[r0 + r][j4 + 2];
            o.w = alpha * o.w + beta * sA2[r0 + r][j4 + 3];
        }
        *(float4*)&C[gr * CH + j4] = o;
    }
}

// ---------------------------------------------------------------------------
extern "C" void kernel_launch(void* const* d_in, const int* in_sizes, int n_in,
                              void* d_out, int out_size, void* d_ws, size_t ws_size,
                              hipStream_t stream) {
    const float* x    = (const float*)d_in[0];
    const int*   ei   = (const int*)d_in[1];
    const float* W1_l = (const float*)d_in[2];
    const float* b1   = (const float*)d_in[3];
    const float* W1_r = (const float*)d_in[4];
    const float* W2_l = (const float*)d_in[5];
    const float* b2   = (const float*)d_in[6];
    const float* W2_r = (const float*)d_in[7];
    const float* Wd   = (const float*)d_in[8];
    const float* bd   = (const float*)d_in[9];
    const float* alpha = (const float*)d_in[10];
    float* out = (float*)d_out;

    const int n = in_sizes[0] / CH;
    const int E = in_sizes[1] / 2;
    const int* src = ei;
    const int* dst = ei + E;

    float* agg = (float*)d_ws;                  // [n, CH]
    float* h   = agg + (size_t)n * CH;          // [n, CH]
    float* deg = h + (size_t)n * CH;            // [n]

    const int scatterBlocks = (E * CH + 255) / 256;
    const int gemmBlocks = (n + 31) / 32;

    // ---- layer 1 ----
    hipMemsetAsync(agg, 0, (size_t)n * CH * sizeof(float), stream);
    hipMemsetAsync(deg, 0, (size_t)n * sizeof(float), stream);
    deg_kernel<<<(E + 255) / 256, 256, 0, stream>>>(dst, deg, E);
    scatter_kernel<<<scatterBlocks, 256, 0, stream>>>(x, src, dst, agg, E);
    gemm_kernel<0><<<gemmBlocks, 256, 0, stream>>>(agg, x, deg, W1_l, W1_r, b1,
                                                   nullptr, h, n);
    // ---- layer 2 ----
    hipMemsetAsync(agg, 0, (size_t)n * CH * sizeof(float), stream);
    scatter_kernel<<<scatterBlocks, 256, 0, stream>>>(h, src, dst, agg, E);
    // in-place: each block reads its own 32 rows fully into LDS before writing
    gemm_kernel<0><<<gemmBlocks, 256, 0, stream>>>(agg, h, deg, W2_l, W2_r, b2,
                                                   nullptr, agg, n);
    // ---- decoder + residual blend ----
    gemm_kernel<1><<<gemmBlocks, 256, 0, stream>>>(agg, x, nullptr, Wd, nullptr,
                                                   bd, alpha, out, n);
}

// Round 3
// 553.766 us; speedup vs baseline: 1.5887x; 1.5887x over previous
//
#include <hip/hip_runtime.h>

#define CH 128

// ---------------------------------------------------------------------------
// cnt[dst] += 1 per edge (int histogram)
__global__ __launch_bounds__(256) void deg_hist_kernel(const int* __restrict__ dst,
                                                       int* __restrict__ cnt, int E) {
    int e = blockIdx.x * 256 + threadIdx.x;
    if (e < E) atomicAdd(&cnt[dst[e]], 1);
}

// ---------------------------------------------------------------------------
// Single-block exclusive scan: rowptr/cursor = exclusive prefix of cnt; rowptr[n]=E.
__global__ __launch_bounds__(512) void scan_kernel(const int* __restrict__ cnt,
                                                   int* __restrict__ rowptr,
                                                   int* __restrict__ cursor, int n) {
    __shared__ int sums[512];
    const int tid = threadIdx.x;
    const int C = (n + 511) / 512;
    const int beg = tid * C;
    const int end = min(beg + C, n);
    int s = 0;
    for (int i = beg; i < end; ++i) s += cnt[i];
    sums[tid] = s;
    __syncthreads();
    // Hillis-Steele inclusive scan over 512 partials (uniform control flow)
    for (int off = 1; off < 512; off <<= 1) {
        int t = (tid >= off) ? sums[tid - off] : 0;
        __syncthreads();
        sums[tid] += t;
        __syncthreads();
    }
    int run = sums[tid] - s;   // exclusive prefix for this thread's span
    for (int i = beg; i < end; ++i) {
        rowptr[i] = run;
        cursor[i] = run;
        run += cnt[i];
    }
    if (tid == 511) rowptr[n] = sums[511];
}

// ---------------------------------------------------------------------------
// col[cursor[dst]++] = src  — bucket edges by destination
__global__ __launch_bounds__(256) void fill_kernel(const int* __restrict__ src,
                                                   const int* __restrict__ dst,
                                                   int* __restrict__ cursor,
                                                   int* __restrict__ col, int E) {
    int e = blockIdx.x * 256 + threadIdx.x;
    if (e < E) {
        int pos = atomicAdd(&cursor[dst[e]], 1);
        col[pos] = src[e];
    }
}

// ---------------------------------------------------------------------------
// Pull aggregation: agg[node,:] = mean over in-neighbors of feat[src,:].
// 32 lanes per node, lane owns float4 of channels; 8 nodes per 256-block.
__global__ __launch_bounds__(256) void gather_kernel(const float* __restrict__ feat,
                                                     const int* __restrict__ rowptr,
                                                     const int* __restrict__ col,
                                                     float* __restrict__ agg, int n) {
    const int node = blockIdx.x * 8 + (threadIdx.x >> 5);
    if (node >= n) return;
    const int c4 = (threadIdx.x & 31) << 2;
    const int beg = rowptr[node];
    const int end = rowptr[node + 1];

    float4 acc0 = make_float4(0.f, 0.f, 0.f, 0.f);
    float4 acc1 = make_float4(0.f, 0.f, 0.f, 0.f);
    int i = beg;
    for (; i + 1 < end; i += 2) {           // 2-way unroll for MLP
        int s0 = col[i], s1 = col[i + 1];
        float4 v0 = *(const float4*)&feat[s0 * CH + c4];
        float4 v1 = *(const float4*)&feat[s1 * CH + c4];
        acc0.x += v0.x; acc0.y += v0.y; acc0.z += v0.z; acc0.w += v0.w;
        acc1.x += v1.x; acc1.y += v1.y; acc1.z += v1.z; acc1.w += v1.w;
    }
    if (i < end) {
        int s0 = col[i];
        float4 v0 = *(const float4*)&feat[s0 * CH + c4];
        acc0.x += v0.x; acc0.y += v0.y; acc0.z += v0.z; acc0.w += v0.w;
    }
    float inv = 1.0f / (float)max(end - beg, 1);
    float4 o;
    o.x = (acc0.x + acc1.x) * inv;
    o.y = (acc0.y + acc1.y) * inv;
    o.z = (acc0.z + acc1.z) * inv;
    o.w = (acc0.w + acc1.w) * inv;
    *(float4*)&agg[node * CH + c4] = o;
}

// ---------------------------------------------------------------------------
// MODE 0:  C = relu( A1 @ Wl + bias + A2 @ Wr )
// MODE 1:  C = alpha * (A1 @ Wl + bias) + (1-alpha) * A2
template <int MODE>
__global__ __launch_bounds__(256) void gemm_kernel(
    const float* __restrict__ A1, const float* __restrict__ A2,
    const float* __restrict__ Wl, const float* __restrict__ Wr,
    const float* __restrict__ bias, const float* __restrict__ alpha_p,
    float* __restrict__ C, int n) {
    __shared__ float sA1[32][CH];
    __shared__ float sA2[32][CH];

    const int tid = threadIdx.x;
    const int rowBase = blockIdx.x * 32;

#pragma unroll
    for (int t = 0; t < 4; ++t) {
        int i  = tid + t * 256;
        int r  = i >> 5;
        int c4 = (i & 31) << 2;
        int gr = rowBase + r;
        float4 v1 = make_float4(0.f, 0.f, 0.f, 0.f);
        float4 v2 = v1;
        if (gr < n) {
            v1 = *(const float4*)&A1[gr * CH + c4];
            v2 = *(const float4*)&A2[gr * CH + c4];
        }
        *(float4*)&sA1[r][c4] = v1;
        *(float4*)&sA2[r][c4] = v2;
    }
    __syncthreads();

    const int j4 = (tid & 31) << 2;
    const int r0 = (tid >> 5) << 2;

    float4 b4 = *(const float4*)&bias[j4];
    float4 acc[4];
#pragma unroll
    for (int r = 0; r < 4; ++r) acc[r] = b4;

    for (int k4 = 0; k4 < CH; k4 += 4) {
        float4 wl0 = *(const float4*)&Wl[(k4 + 0) * CH + j4];
        float4 wl1 = *(const float4*)&Wl[(k4 + 1) * CH + j4];
        float4 wl2 = *(const float4*)&Wl[(k4 + 2) * CH + j4];
        float4 wl3 = *(const float4*)&Wl[(k4 + 3) * CH + j4];
#pragma unroll
        for (int r = 0; r < 4; ++r) {
            float4 a1 = *(const float4*)&sA1[r0 + r][k4];
            acc[r].x += a1.x * wl0.x + a1.y * wl1.x + a1.z * wl2.x + a1.w * wl3.x;
            acc[r].y += a1.x * wl0.y + a1.y * wl1.y + a1.z * wl2.y + a1.w * wl3.y;
            acc[r].z += a1.x * wl0.z + a1.y * wl1.z + a1.z * wl2.z + a1.w * wl3.z;
            acc[r].w += a1.x * wl0.w + a1.y * wl1.w + a1.z * wl2.w + a1.w * wl3.w;
        }
        if (MODE == 0) {
            float4 wr0 = *(const float4*)&Wr[(k4 + 0) * CH + j4];
            float4 wr1 = *(const float4*)&Wr[(k4 + 1) * CH + j4];
            float4 wr2 = *(const float4*)&Wr[(k4 + 2) * CH + j4];
            float4 wr3 = *(const float4*)&Wr[(k4 + 3) * CH + j4];
#pragma unroll
            for (int r = 0; r < 4; ++r) {
                float4 a2 = *(const float4*)&sA2[r0 + r][k4];
                acc[r].x += a2.x * wr0.x + a2.y * wr1.x + a2.z * wr2.x + a2.w * wr3.x;
                acc[r].y += a2.x * wr0.y + a2.y * wr1.y + a2.z * wr2.y + a2.w * wr3.y;
                acc[r].z += a2.x * wr0.z + a2.y * wr1.z + a2.z * wr2.z + a2.w * wr3.z;
                acc[r].w += a2.x * wr0.w + a2.y * wr1.w + a2.z * wr2.w + a2.w * wr3.w;
            }
        }
    }

    float alpha = 0.f, beta = 0.f;
    if (MODE == 1) { alpha = alpha_p[0]; beta = 1.0f - alpha; }

#pragma unroll
    for (int r = 0; r < 4; ++r) {
        int gr = rowBase + r0 + r;
        if (gr >= n) continue;
        float4 o = acc[r];
        if (MODE == 0) {
            o.x = fmaxf(o.x, 0.f); o.y = fmaxf(o.y, 0.f);
            o.z = fmaxf(o.z, 0.f); o.w = fmaxf(o.w, 0.f);
        } else {
            o.x = alpha * o.x + beta * sA2[r0 + r][j4 + 0];
            o.y = alpha * o.y + beta * sA2[r0 + r][j4 + 1];
            o.z = alpha * o.z + beta * sA2[r0 + r][j4 + 2];
            o.w = alpha * o.w + beta * sA2[r0 + r][j4 + 3];
        }
        *(float4*)&C[gr * CH + j4] = o;
    }
}

// ---------------------------------------------------------------------------
extern "C" void kernel_launch(void* const* d_in, const int* in_sizes, int n_in,
                              void* d_out, int out_size, void* d_ws, size_t ws_size,
                              hipStream_t stream) {
    const float* x    = (const float*)d_in[0];
    const int*   ei   = (const int*)d_in[1];
    const float* W1_l = (const float*)d_in[2];
    const float* b1   = (const float*)d_in[3];
    const float* W1_r = (const float*)d_in[4];
    const float* W2_l = (const float*)d_in[5];
    const float* b2   = (const float*)d_in[6];
    const float* W2_r = (const float*)d_in[7];
    const float* Wd   = (const float*)d_in[8];
    const float* bd   = (const float*)d_in[9];
    const float* alpha = (const float*)d_in[10];
    float* out = (float*)d_out;

    const int n = in_sizes[0] / CH;
    const int E = in_sizes[1] / 2;
    const int* src = ei;
    const int* dst = ei + E;

    float* agg    = (float*)d_ws;                        // [n, CH]
    float* h      = agg + (size_t)n * CH;                // [n, CH]
    int*   cnt    = (int*)(h + (size_t)n * CH);          // [n]
    int*   rowptr = cnt + n;                             // [n+1]
    int*   cursor = rowptr + n + 1;                      // [n]
    int*   col    = cursor + n;                          // [E]

    const int edgeBlocks = (E + 255) / 256;
    const int gatherBlocks = (n + 7) / 8;
    const int gemmBlocks = (n + 31) / 32;

    // ---- CSR build (per call; edge_index constant but ws is re-poisoned) ----
    hipMemsetAsync(cnt, 0, (size_t)n * sizeof(int), stream);
    deg_hist_kernel<<<edgeBlocks, 256, 0, stream>>>(dst, cnt, E);
    scan_kernel<<<1, 512, 0, stream>>>(cnt, rowptr, cursor, n);
    fill_kernel<<<edgeBlocks, 256, 0, stream>>>(src, dst, cursor, col, E);

    // ---- layer 1 ----
    gather_kernel<<<gatherBlocks, 256, 0, stream>>>(x, rowptr, col, agg, n);
    gemm_kernel<0><<<gemmBlocks, 256, 0, stream>>>(agg, x, W1_l, W1_r, b1,
                                                   nullptr, h, n);
    // ---- layer 2 ----
    gather_kernel<<<gatherBlocks, 256, 0, stream>>>(h, rowptr, col, agg, n);
    gemm_kernel<0><<<gemmBlocks, 256, 0, stream>>>(agg, h, W2_l, W2_r, b2,
                                                   nullptr, agg, n);
    // ---- decoder + residual blend ----
    gemm_kernel<1><<<gemmBlocks, 256, 0, stream>>>(agg, x, Wd, nullptr,
                                                   bd, alpha, out, n);
}

// Round 4
// 443.432 us; speedup vs baseline: 1.9839x; 1.2488x over previous
//
#include <hip/hip_runtime.h>

#define CH 128
#define SCAN_B 256   // elements per scan block

// ---------------------------------------------------------------------------
// cnt[dst] += 1 per edge (int histogram)
__global__ __launch_bounds__(256) void deg_hist_kernel(const int* __restrict__ dst,
                                                       int* __restrict__ cnt, int E) {
    int e = blockIdx.x * 256 + threadIdx.x;
    if (e < E) atomicAdd(&cnt[dst[e]], 1);
}

// ---------------------------------------------------------------------------
// Phase 1: per-block sums of cnt chunks
__global__ __launch_bounds__(256) void scan_partial_kernel(const int* __restrict__ cnt,
                                                           int* __restrict__ blockSums,
                                                           int n) {
    __shared__ int red[256];
    const int tid = threadIdx.x;
    const int i = blockIdx.x * SCAN_B + tid;
    red[tid] = (i < n) ? cnt[i] : 0;
    __syncthreads();
#pragma unroll
    for (int off = 128; off > 0; off >>= 1) {
        if (tid < off) red[tid] += red[tid + off];
        __syncthreads();
    }
    if (tid == 0) blockSums[blockIdx.x] = red[0];
}

// ---------------------------------------------------------------------------
// Phase 2: single-block exclusive scan of B block sums (B <= 1024)
__global__ __launch_bounds__(1024) void scan_blocksums_kernel(const int* __restrict__ blockSums,
                                                              int* __restrict__ blockOffsets,
                                                              int B) {
    __shared__ int s[1024];
    const int tid = threadIdx.x;
    int v = (tid < B) ? blockSums[tid] : 0;
    s[tid] = v;
    __syncthreads();
    for (int off = 1; off < 1024; off <<= 1) {
        int t = (tid >= off) ? s[tid - off] : 0;
        __syncthreads();
        s[tid] += t;
        __syncthreads();
    }
    if (tid < B) blockOffsets[tid] = s[tid] - v;   // exclusive prefix
}

// ---------------------------------------------------------------------------
// Phase 3: per-chunk exclusive scan + block offset -> rowptr, cursor
__global__ __launch_bounds__(256) void scan_final_kernel(const int* __restrict__ cnt,
                                                         const int* __restrict__ blockOffsets,
                                                         int* __restrict__ rowptr,
                                                         int* __restrict__ cursor,
                                                         int n, int E) {
    __shared__ int s[256];
    const int tid = threadIdx.x;
    const int i = blockIdx.x * SCAN_B + tid;
    int v = (i < n) ? cnt[i] : 0;
    s[tid] = v;
    __syncthreads();
    for (int off = 1; off < 256; off <<= 1) {
        int t = (tid >= off) ? s[tid - off] : 0;
        __syncthreads();
        s[tid] += t;
        __syncthreads();
    }
    if (i < n) {
        int ex = blockOffsets[blockIdx.x] + s[tid] - v;
        rowptr[i] = ex;
        cursor[i] = ex;
    }
    if (blockIdx.x == 0 && tid == 0) rowptr[n] = E;
}

// ---------------------------------------------------------------------------
// col[cursor[dst]++] = src  — bucket edges by destination
__global__ __launch_bounds__(256) void fill_kernel(const int* __restrict__ src,
                                                   const int* __restrict__ dst,
                                                   int* __restrict__ cursor,
                                                   int* __restrict__ col, int E) {
    int e = blockIdx.x * 256 + threadIdx.x;
    if (e < E) {
        int pos = atomicAdd(&cursor[dst[e]], 1);
        col[pos] = src[e];
    }
}

// ---------------------------------------------------------------------------
// Pull aggregation: agg[node,:] = mean over in-neighbors of feat[src,:].
// 32 lanes per node, lane owns float4 of channels; 8 nodes per 256-block.
__global__ __launch_bounds__(256) void gather_kernel(const float* __restrict__ feat,
                                                     const int* __restrict__ rowptr,
                                                     const int* __restrict__ col,
                                                     float* __restrict__ agg, int n) {
    const int node = blockIdx.x * 8 + (threadIdx.x >> 5);
    if (node >= n) return;
    const int c4 = (threadIdx.x & 31) << 2;
    const int beg = rowptr[node];
    const int end = rowptr[node + 1];

    float4 acc0 = make_float4(0.f, 0.f, 0.f, 0.f);
    float4 acc1 = make_float4(0.f, 0.f, 0.f, 0.f);
    int i = beg;
    for (; i + 1 < end; i += 2) {           // 2-way unroll for MLP
        int s0 = col[i], s1 = col[i + 1];
        float4 v0 = *(const float4*)&feat[s0 * CH + c4];
        float4 v1 = *(const float4*)&feat[s1 * CH + c4];
        acc0.x += v0.x; acc0.y += v0.y; acc0.z += v0.z; acc0.w += v0.w;
        acc1.x += v1.x; acc1.y += v1.y; acc1.z += v1.z; acc1.w += v1.w;
    }
    if (i < end) {
        int s0 = col[i];
        float4 v0 = *(const float4*)&feat[s0 * CH + c4];
        acc0.x += v0.x; acc0.y += v0.y; acc0.z += v0.z; acc0.w += v0.w;
    }
    float inv = 1.0f / (float)max(end - beg, 1);
    float4 o;
    o.x = (acc0.x + acc1.x) * inv;
    o.y = (acc0.y + acc1.y) * inv;
    o.z = (acc0.z + acc1.z) * inv;
    o.w = (acc0.w + acc1.w) * inv;
    *(float4*)&agg[node * CH + c4] = o;
}

// ---------------------------------------------------------------------------
// MODE 0:  C = relu( A1 @ Wl + bias + A2 @ Wr )
// MODE 1:  C = alpha * (A1 @ Wl + bias) + (1-alpha) * A2
template <int MODE>
__global__ __launch_bounds__(256) void gemm_kernel(
    const float* __restrict__ A1, const float* __restrict__ A2,
    const float* __restrict__ Wl, const float* __restrict__ Wr,
    const float* __restrict__ bias, const float* __restrict__ alpha_p,
    float* __restrict__ C, int n) {
    __shared__ float sA1[32][CH];
    __shared__ float sA2[32][CH];

    const int tid = threadIdx.x;
    const int rowBase = blockIdx.x * 32;

#pragma unroll
    for (int t = 0; t < 4; ++t) {
        int i  = tid + t * 256;
        int r  = i >> 5;
        int c4 = (i & 31) << 2;
        int gr = rowBase + r;
        float4 v1 = make_float4(0.f, 0.f, 0.f, 0.f);
        float4 v2 = v1;
        if (gr < n) {
            v1 = *(const float4*)&A1[gr * CH + c4];
            v2 = *(const float4*)&A2[gr * CH + c4];
        }
        *(float4*)&sA1[r][c4] = v1;
        *(float4*)&sA2[r][c4] = v2;
    }
    __syncthreads();

    const int j4 = (tid & 31) << 2;
    const int r0 = (tid >> 5) << 2;

    float4 b4 = *(const float4*)&bias[j4];
    float4 acc[4];
#pragma unroll
    for (int r = 0; r < 4; ++r) acc[r] = b4;

    for (int k4 = 0; k4 < CH; k4 += 4) {
        float4 wl0 = *(const float4*)&Wl[(k4 + 0) * CH + j4];
        float4 wl1 = *(const float4*)&Wl[(k4 + 1) * CH + j4];
        float4 wl2 = *(const float4*)&Wl[(k4 + 2) * CH + j4];
        float4 wl3 = *(const float4*)&Wl[(k4 + 3) * CH + j4];
#pragma unroll
        for (int r = 0; r < 4; ++r) {
            float4 a1 = *(const float4*)&sA1[r0 + r][k4];
            acc[r].x += a1.x * wl0.x + a1.y * wl1.x + a1.z * wl2.x + a1.w * wl3.x;
            acc[r].y += a1.x * wl0.y + a1.y * wl1.y + a1.z * wl2.y + a1.w * wl3.y;
            acc[r].z += a1.x * wl0.z + a1.y * wl1.z + a1.z * wl2.z + a1.w * wl3.z;
            acc[r].w += a1.x * wl0.w + a1.y * wl1.w + a1.z * wl2.w + a1.w * wl3.w;
        }
        if (MODE == 0) {
            float4 wr0 = *(const float4*)&Wr[(k4 + 0) * CH + j4];
            float4 wr1 = *(const float4*)&Wr[(k4 + 1) * CH + j4];
            float4 wr2 = *(const float4*)&Wr[(k4 + 2) * CH + j4];
            float4 wr3 = *(const float4*)&Wr[(k4 + 3) * CH + j4];
#pragma unroll
            for (int r = 0; r < 4; ++r) {
                float4 a2 = *(const float4*)&sA2[r0 + r][k4];
                acc[r].x += a2.x * wr0.x + a2.y * wr1.x + a2.z * wr2.x + a2.w * wr3.x;
                acc[r].y += a2.x * wr0.y + a2.y * wr1.y + a2.z * wr2.y + a2.w * wr3.y;
                acc[r].z += a2.x * wr0.z + a2.y * wr1.z + a2.z * wr2.z + a2.w * wr3.z;
                acc[r].w += a2.x * wr0.w + a2.y * wr1.w + a2.z * wr2.w + a2.w * wr3.w;
            }
        }
    }

    float alpha = 0.f, beta = 0.f;
    if (MODE == 1) { alpha = alpha_p[0]; beta = 1.0f - alpha; }

#pragma unroll
    for (int r = 0; r < 4; ++r) {
        int gr = rowBase + r0 + r;
        if (gr >= n) continue;
        float4 o = acc[r];
        if (MODE == 0) {
            o.x = fmaxf(o.x, 0.f); o.y = fmaxf(o.y, 0.f);
            o.z = fmaxf(o.z, 0.f); o.w = fmaxf(o.w, 0.f);
        } else {
            o.x = alpha * o.x + beta * sA2[r0 + r][j4 + 0];
            o.y = alpha * o.y + beta * sA2[r0 + r][j4 + 1];
            o.z = alpha * o.z + beta * sA2[r0 + r][j4 + 2];
            o.w = alpha * o.w + beta * sA2[r0 + r][j4 + 3];
        }
        *(float4*)&C[gr * CH + j4] = o;
    }
}

// ---------------------------------------------------------------------------
extern "C" void kernel_launch(void* const* d_in, const int* in_sizes, int n_in,
                              void* d_out, int out_size, void* d_ws, size_t ws_size,
                              hipStream_t stream) {
    const float* x    = (const float*)d_in[0];
    const int*   ei   = (const int*)d_in[1];
    const float* W1_l = (const float*)d_in[2];
    const float* b1   = (const float*)d_in[3];
    const float* W1_r = (const float*)d_in[4];
    const float* W2_l = (const float*)d_in[5];
    const float* b2   = (const float*)d_in[6];
    const float* W2_r = (const float*)d_in[7];
    const float* Wd   = (const float*)d_in[8];
    const float* bd   = (const float*)d_in[9];
    const float* alpha = (const float*)d_in[10];
    float* out = (float*)d_out;

    const int n = in_sizes[0] / CH;
    const int E = in_sizes[1] / 2;
    const int* src = ei;
    const int* dst = ei + E;

    const int scanBlocks = (n + SCAN_B - 1) / SCAN_B;   // 196 for n=50000

    float* agg    = (float*)d_ws;                        // [n, CH]
    float* h      = agg + (size_t)n * CH;                // [n, CH]
    int*   cnt    = (int*)(h + (size_t)n * CH);          // [n]
    int*   rowptr = cnt + n;                             // [n+1]
    int*   cursor = rowptr + n + 1;                      // [n]
    int*   col    = cursor + n;                          // [E]
    int*   bsums  = col + E;                             // [scanBlocks]
    int*   boffs  = bsums + scanBlocks;                  // [scanBlocks]

    const int edgeBlocks = (E + 255) / 256;
    const int gatherBlocks = (n + 7) / 8;
    const int gemmBlocks = (n + 31) / 32;

    // ---- CSR build (per call; ws is re-poisoned every timed launch) ----
    hipMemsetAsync(cnt, 0, (size_t)n * sizeof(int), stream);
    deg_hist_kernel<<<edgeBlocks, 256, 0, stream>>>(dst, cnt, E);
    scan_partial_kernel<<<scanBlocks, 256, 0, stream>>>(cnt, bsums, n);
    scan_blocksums_kernel<<<1, 1024, 0, stream>>>(bsums, boffs, scanBlocks);
    scan_final_kernel<<<scanBlocks, 256, 0, stream>>>(cnt, boffs, rowptr, cursor, n, E);
    fill_kernel<<<edgeBlocks, 256, 0, stream>>>(src, dst, cursor, col, E);

    // ---- layer 1 ----
    gather_kernel<<<gatherBlocks, 256, 0, stream>>>(x, rowptr, col, agg, n);
    gemm_kernel<0><<<gemmBlocks, 256, 0, stream>>>(agg, x, W1_l, W1_r, b1,
                                                   nullptr, h, n);
    // ---- layer 2 ----
    gather_kernel<<<gatherBlocks, 256, 0, stream>>>(h, rowptr, col, agg, n);
    gemm_kernel<0><<<gemmBlocks, 256, 0, stream>>>(agg, h, W2_l, W2_r, b2,
                                                   nullptr, agg, n);
    // ---- decoder + residual blend ----
    gemm_kernel<1><<<gemmBlocks, 256, 0, stream>>>(agg, x, Wd, nullptr,
                                                   bd, alpha, out, n);
}

// Round 5
// 395.601 us; speedup vs baseline: 2.2238x; 1.1209x over previous
//
#include <hip/hip_runtime.h>

#define CH 128
#define SCAN_B 256   // elements per scan block
#define TM 64        // GEMM rows per block tile
#define KC 32        // GEMM k-chunk

// ---------------------------------------------------------------------------
// cnt[dst] += 1 per edge (int histogram)
__global__ __launch_bounds__(256) void deg_hist_kernel(const int* __restrict__ dst,
                                                       int* __restrict__ cnt, int E) {
    int e = blockIdx.x * 256 + threadIdx.x;
    if (e < E) atomicAdd(&cnt[dst[e]], 1);
}

// ---------------------------------------------------------------------------
// Phase 1: per-block sums of cnt chunks
__global__ __launch_bounds__(256) void scan_partial_kernel(const int* __restrict__ cnt,
                                                           int* __restrict__ blockSums,
                                                           int n) {
    __shared__ int red[256];
    const int tid = threadIdx.x;
    const int i = blockIdx.x * SCAN_B + tid;
    red[tid] = (i < n) ? cnt[i] : 0;
    __syncthreads();
#pragma unroll
    for (int off = 128; off > 0; off >>= 1) {
        if (tid < off) red[tid] += red[tid + off];
        __syncthreads();
    }
    if (tid == 0) blockSums[blockIdx.x] = red[0];
}

// ---------------------------------------------------------------------------
// Phase 2: single-block exclusive scan of B block sums (B <= 1024)
__global__ __launch_bounds__(1024) void scan_blocksums_kernel(const int* __restrict__ blockSums,
                                                              int* __restrict__ blockOffsets,
                                                              int B) {
    __shared__ int s[1024];
    const int tid = threadIdx.x;
    int v = (tid < B) ? blockSums[tid] : 0;
    s[tid] = v;
    __syncthreads();
    for (int off = 1; off < 1024; off <<= 1) {
        int t = (tid >= off) ? s[tid - off] : 0;
        __syncthreads();
        s[tid] += t;
        __syncthreads();
    }
    if (tid < B) blockOffsets[tid] = s[tid] - v;   // exclusive prefix
}

// ---------------------------------------------------------------------------
// Phase 3: per-chunk exclusive scan + block offset -> rowptr, cursor
__global__ __launch_bounds__(256) void scan_final_kernel(const int* __restrict__ cnt,
                                                         const int* __restrict__ blockOffsets,
                                                         int* __restrict__ rowptr,
                                                         int* __restrict__ cursor,
                                                         int n, int E) {
    __shared__ int s[256];
    const int tid = threadIdx.x;
    const int i = blockIdx.x * SCAN_B + tid;
    int v = (i < n) ? cnt[i] : 0;
    s[tid] = v;
    __syncthreads();
    for (int off = 1; off < 256; off <<= 1) {
        int t = (tid >= off) ? s[tid - off] : 0;
        __syncthreads();
        s[tid] += t;
        __syncthreads();
    }
    if (i < n) {
        int ex = blockOffsets[blockIdx.x] + s[tid] - v;
        rowptr[i] = ex;
        cursor[i] = ex;
    }
    if (blockIdx.x == 0 && tid == 0) rowptr[n] = E;
}

// ---------------------------------------------------------------------------
// col[cursor[dst]++] = src  — bucket edges by destination
__global__ __launch_bounds__(256) void fill_kernel(const int* __restrict__ src,
                                                   const int* __restrict__ dst,
                                                   int* __restrict__ cursor,
                                                   int* __restrict__ col, int E) {
    int e = blockIdx.x * 256 + threadIdx.x;
    if (e < E) {
        int pos = atomicAdd(&cursor[dst[e]], 1);
        col[pos] = src[e];
    }
}

// ---------------------------------------------------------------------------
// Pull aggregation: agg[node,:] = mean over in-neighbors of feat[src,:].
__global__ __launch_bounds__(256) void gather_kernel(const float* __restrict__ feat,
                                                     const int* __restrict__ rowptr,
                                                     const int* __restrict__ col,
                                                     float* __restrict__ agg, int n) {
    const int node = blockIdx.x * 8 + (threadIdx.x >> 5);
    if (node >= n) return;
    const int c4 = (threadIdx.x & 31) << 2;
    const int beg = rowptr[node];
    const int end = rowptr[node + 1];

    float4 acc0 = make_float4(0.f, 0.f, 0.f, 0.f);
    float4 acc1 = make_float4(0.f, 0.f, 0.f, 0.f);
    int i = beg;
    for (; i + 1 < end; i += 2) {
        int s0 = col[i], s1 = col[i + 1];
        float4 v0 = *(const float4*)&feat[s0 * CH + c4];
        float4 v1 = *(const float4*)&feat[s1 * CH + c4];
        acc0.x += v0.x; acc0.y += v0.y; acc0.z += v0.z; acc0.w += v0.w;
        acc1.x += v1.x; acc1.y += v1.y; acc1.z += v1.z; acc1.w += v1.w;
    }
    if (i < end) {
        int s0 = col[i];
        float4 v0 = *(const float4*)&feat[s0 * CH + c4];
        acc0.x += v0.x; acc0.y += v0.y; acc0.z += v0.z; acc0.w += v0.w;
    }
    float inv = 1.0f / (float)max(end - beg, 1);
    float4 o;
    o.x = (acc0.x + acc1.x) * inv;
    o.y = (acc0.y + acc1.y) * inv;
    o.z = (acc0.z + acc1.z) * inv;
    o.w = (acc0.w + acc1.w) * inv;
    *(float4*)&agg[node * CH + c4] = o;
}

// ---------------------------------------------------------------------------
// GEMM v2: virtual-K LDS-staged.
// MODE 0:  C = relu( A1 @ Wl + A2 @ Wr + bias )          (K = 256 virtual)
// MODE 1:  C = alpha * (A1 @ Wl + bias) + (1-alpha)*resid (K = 128)
// Block 256 threads = tile 64 rows x 128 cols; thread = 8 rows x 4 cols.
// A staged k-major with +1 row pad (<=2-way bank alias = free);
// W staged [KC][CH], read via ds_read_b128 broadcast.
template <int MODE>
__global__ __launch_bounds__(256) void gemm_kernel(
    const float* __restrict__ A1, const float* __restrict__ A2,
    const float* __restrict__ Wl, const float* __restrict__ Wr,
    const float* __restrict__ bias, const float* __restrict__ alpha_p,
    const float* __restrict__ resid,
    float* __restrict__ C, int n) {
    __shared__ float sA[KC * (TM + 1)];   // k-major, padded: 8.3 KB
    __shared__ float sW[KC * CH];         // 16 KB

    const int tid = threadIdx.x;
    const int rowBase = blockIdx.x * TM;
    const int j4 = (tid & 31) << 2;       // output cols j4..j4+3
    const int r0 = (tid >> 5) << 3;       // output rows r0..r0+7 (tile-local)

    float acc[8][4];
#pragma unroll
    for (int r = 0; r < 8; ++r)
#pragma unroll
        for (int c = 0; c < 4; ++c) acc[r][c] = 0.f;

    const int KTOT = (MODE == 0) ? 2 * CH : CH;
    for (int kb = 0; kb < KTOT; kb += KC) {
        const float* Asrc = A1;
        const float* Wsrc = Wl;
        int kof = kb;
        if (MODE == 0 && kb >= CH) { Asrc = A2; Wsrc = Wr; kof = kb - CH; }

        __syncthreads();   // protect LDS from previous chunk's readers

        // stage A chunk [64 rows][KC k] -> transposed sA[k][row]
#pragma unroll
        for (int t = 0; t < 2; ++t) {
            int idx = tid + t * 256;       // 0..511
            int row = idx >> 3;            // 0..63
            int kq  = idx & 7;             // 0..7  (float4 of k)
            int gr = rowBase + row;
            float4 v = make_float4(0.f, 0.f, 0.f, 0.f);
            if (gr < n) v = *(const float4*)&Asrc[(size_t)gr * CH + kof + (kq << 2)];
            sA[((kq << 2) + 0) * (TM + 1) + row] = v.x;
            sA[((kq << 2) + 1) * (TM + 1) + row] = v.y;
            sA[((kq << 2) + 2) * (TM + 1) + row] = v.z;
            sA[((kq << 2) + 3) * (TM + 1) + row] = v.w;
        }
        // stage W chunk [KC][CH]
#pragma unroll
        for (int t = 0; t < 4; ++t) {
            int idx = tid + t * 256;       // 0..1023
            int kr = idx >> 5;             // 0..31
            int q4 = (idx & 31) << 2;      // 0..124
            *(float4*)&sW[kr * CH + q4] =
                *(const float4*)&Wsrc[(size_t)(kof + kr) * CH + q4];
        }
        __syncthreads();

#pragma unroll 8
        for (int k = 0; k < KC; ++k) {
            float4 w = *(const float4*)&sW[k * CH + j4];
            const float* ar = &sA[k * (TM + 1) + r0];
#pragma unroll
            for (int r = 0; r < 8; ++r) {
                float a = ar[r];
                acc[r][0] += a * w.x;
                acc[r][1] += a * w.y;
                acc[r][2] += a * w.z;
                acc[r][3] += a * w.w;
            }
        }
    }

    float4 b4 = *(const float4*)&bias[j4];
    float alpha = 0.f, beta = 0.f;
    if (MODE == 1) { alpha = alpha_p[0]; beta = 1.0f - alpha; }

#pragma unroll
    for (int r = 0; r < 8; ++r) {
        int gr = rowBase + r0 + r;
        if (gr >= n) continue;
        float4 o;
        o.x = acc[r][0] + b4.x;
        o.y = acc[r][1] + b4.y;
        o.z = acc[r][2] + b4.z;
        o.w = acc[r][3] + b4.w;
        if (MODE == 0) {
            o.x = fmaxf(o.x, 0.f); o.y = fmaxf(o.y, 0.f);
            o.z = fmaxf(o.z, 0.f); o.w = fmaxf(o.w, 0.f);
        } else {
            float4 rx = *(const float4*)&resid[(size_t)gr * CH + j4];
            o.x = alpha * o.x + beta * rx.x;
            o.y = alpha * o.y + beta * rx.y;
            o.z = alpha * o.z + beta * rx.z;
            o.w = alpha * o.w + beta * rx.w;
        }
        *(float4*)&C[(size_t)gr * CH + j4] = o;
    }
}

// ---------------------------------------------------------------------------
extern "C" void kernel_launch(void* const* d_in, const int* in_sizes, int n_in,
                              void* d_out, int out_size, void* d_ws, size_t ws_size,
                              hipStream_t stream) {
    const float* x    = (const float*)d_in[0];
    const int*   ei   = (const int*)d_in[1];
    const float* W1_l = (const float*)d_in[2];
    const float* b1   = (const float*)d_in[3];
    const float* W1_r = (const float*)d_in[4];
    const float* W2_l = (const float*)d_in[5];
    const float* b2   = (const float*)d_in[6];
    const float* W2_r = (const float*)d_in[7];
    const float* Wd   = (const float*)d_in[8];
    const float* bd   = (const float*)d_in[9];
    const float* alpha = (const float*)d_in[10];
    float* out = (float*)d_out;

    const int n = in_sizes[0] / CH;
    const int E = in_sizes[1] / 2;
    const int* src = ei;
    const int* dst = ei + E;

    const int scanBlocks = (n + SCAN_B - 1) / SCAN_B;   // 196 for n=50000

    float* agg    = (float*)d_ws;                        // [n, CH]
    float* h      = agg + (size_t)n * CH;                // [n, CH]
    int*   cnt    = (int*)(h + (size_t)n * CH);          // [n]
    int*   rowptr = cnt + n;                             // [n+1]
    int*   cursor = rowptr + n + 1;                      // [n]
    int*   col    = cursor + n;                          // [E]
    int*   bsums  = col + E;                             // [scanBlocks]
    int*   boffs  = bsums + scanBlocks;                  // [scanBlocks]

    const int edgeBlocks = (E + 255) / 256;
    const int gatherBlocks = (n + 7) / 8;
    const int gemmBlocks = (n + TM - 1) / TM;            // 782

    // ---- CSR build (per call; ws is re-poisoned every timed launch) ----
    hipMemsetAsync(cnt, 0, (size_t)n * sizeof(int), stream);
    deg_hist_kernel<<<edgeBlocks, 256, 0, stream>>>(dst, cnt, E);
    scan_partial_kernel<<<scanBlocks, 256, 0, stream>>>(cnt, bsums, n);
    scan_blocksums_kernel<<<1, 1024, 0, stream>>>(bsums, boffs, scanBlocks);
    scan_final_kernel<<<scanBlocks, 256, 0, stream>>>(cnt, boffs, rowptr, cursor, n, E);
    fill_kernel<<<edgeBlocks, 256, 0, stream>>>(src, dst, cursor, col, E);

    // ---- layer 1: h = relu(agg(x)@W1_l + b1 + x@W1_r) ----
    gather_kernel<<<gatherBlocks, 256, 0, stream>>>(x, rowptr, col, agg, n);
    gemm_kernel<0><<<gemmBlocks, 256, 0, stream>>>(agg, x, W1_l, W1_r, b1,
                                                   nullptr, nullptr, h, n);
    // ---- layer 2: agg = relu(agg(h)@W2_l + b2 + h@W2_r) ----
    gather_kernel<<<gatherBlocks, 256, 0, stream>>>(h, rowptr, col, agg, n);
    gemm_kernel<0><<<gemmBlocks, 256, 0, stream>>>(agg, h, W2_l, W2_r, b2,
                                                   nullptr, nullptr, agg, n);
    // ---- decoder + residual: out = alpha*(agg@Wd + bd) + (1-alpha)*x ----
    gemm_kernel<1><<<gemmBlocks, 256, 0, stream>>>(agg, nullptr, Wd, nullptr,
                                                   bd, alpha, x, out, n);
}

// Round 6
// 289.350 us; speedup vs baseline: 3.0404x; 1.3672x over previous
//
#include <hip/hip_runtime.h>

#define CH 128
#define SCAN_B 256

typedef short bf16x8 __attribute__((ext_vector_type(8)));
typedef float f32x4 __attribute__((ext_vector_type(4)));

static __device__ __forceinline__ unsigned short f2bf(float f) {
    unsigned int u = __float_as_uint(f);
    u = (u + 0x7fff + ((u >> 16) & 1)) >> 16;   // RNE
    return (unsigned short)u;
}
static __device__ __forceinline__ float bf2f(unsigned short s) {
    return __uint_as_float(((unsigned int)s) << 16);
}

// ---------------------------------------------------------------------------
__global__ __launch_bounds__(256) void deg_hist_kernel(const int* __restrict__ dst,
                                                       int* __restrict__ cnt, int E) {
    int e = blockIdx.x * 256 + threadIdx.x;
    if (e < E) atomicAdd(&cnt[dst[e]], 1);
}

__global__ __launch_bounds__(256) void scan_partial_kernel(const int* __restrict__ cnt,
                                                           int* __restrict__ blockSums,
                                                           int n) {
    __shared__ int red[256];
    const int tid = threadIdx.x;
    const int i = blockIdx.x * SCAN_B + tid;
    red[tid] = (i < n) ? cnt[i] : 0;
    __syncthreads();
#pragma unroll
    for (int off = 128; off > 0; off >>= 1) {
        if (tid < off) red[tid] += red[tid + off];
        __syncthreads();
    }
    if (tid == 0) blockSums[blockIdx.x] = red[0];
}

__global__ __launch_bounds__(1024) void scan_blocksums_kernel(const int* __restrict__ blockSums,
                                                              int* __restrict__ blockOffsets,
                                                              int B) {
    __shared__ int s[1024];
    const int tid = threadIdx.x;
    int v = (tid < B) ? blockSums[tid] : 0;
    s[tid] = v;
    __syncthreads();
    for (int off = 1; off < 1024; off <<= 1) {
        int t = (tid >= off) ? s[tid - off] : 0;
        __syncthreads();
        s[tid] += t;
        __syncthreads();
    }
    if (tid < B) blockOffsets[tid] = s[tid] - v;
}

__global__ __launch_bounds__(256) void scan_final_kernel(const int* __restrict__ cnt,
                                                         const int* __restrict__ blockOffsets,
                                                         int* __restrict__ rowptr,
                                                         int* __restrict__ cursor,
                                                         int n, int E) {
    __shared__ int s[256];
    const int tid = threadIdx.x;
    const int i = blockIdx.x * SCAN_B + tid;
    int v = (i < n) ? cnt[i] : 0;
    s[tid] = v;
    __syncthreads();
    for (int off = 1; off < 256; off <<= 1) {
        int t = (tid >= off) ? s[tid - off] : 0;
        __syncthreads();
        s[tid] += t;
        __syncthreads();
    }
    if (i < n) {
        int ex = blockOffsets[blockIdx.x] + s[tid] - v;
        rowptr[i] = ex;
        cursor[i] = ex;
    }
    if (blockIdx.x == 0 && tid == 0) rowptr[n] = E;
}

__global__ __launch_bounds__(256) void fill_kernel(const int* __restrict__ src,
                                                   const int* __restrict__ dst,
                                                   int* __restrict__ cursor,
                                                   int* __restrict__ col, int E) {
    int e = blockIdx.x * 256 + threadIdx.x;
    if (e < E) {
        int pos = atomicAdd(&cursor[dst[e]], 1);
        col[pos] = src[e];
    }
}

// ---------------------------------------------------------------------------
// fp32 -> bf16 feature conversion (4 elems/thread)
__global__ __launch_bounds__(256) void conv_x_kernel(const float* __restrict__ x,
                                                     unsigned short* __restrict__ xb,
                                                     int total4) {
    int idx = blockIdx.x * 256 + threadIdx.x;
    if (idx < total4) {
        float4 v = ((const float4*)x)[idx];
        ushort4 o;
        o.x = f2bf(v.x); o.y = f2bf(v.y); o.z = f2bf(v.z); o.w = f2bf(v.w);
        ((ushort4*)xb)[idx] = o;
    }
}

// fp32 [k][n] -> bf16 transposed [n][k] for 5 weight matrices (blockIdx.y picks)
__global__ __launch_bounds__(256) void conv_wt_kernel(
    const float* __restrict__ w0, const float* __restrict__ w1,
    const float* __restrict__ w2, const float* __restrict__ w3,
    const float* __restrict__ w4,
    unsigned short* __restrict__ t0, unsigned short* __restrict__ t1,
    unsigned short* __restrict__ t2, unsigned short* __restrict__ t3,
    unsigned short* __restrict__ t4) {
    const float* W; unsigned short* T;
    switch (blockIdx.y) {
        case 0: W = w0; T = t0; break;
        case 1: W = w1; T = t1; break;
        case 2: W = w2; T = t2; break;
        case 3: W = w3; T = t3; break;
        default: W = w4; T = t4; break;
    }
    int idx = blockIdx.x * 256 + threadIdx.x;   // 0..16383
    int k = idx >> 7, nn = idx & 127;
    T[nn * CH + k] = f2bf(W[idx]);
}

// ---------------------------------------------------------------------------
// Pull mean-aggregation, bf16 in/out, fp32 accumulate.
// 32 lanes/node, lane owns 4 channels (ushort4 = 8B/neighbor-row).
__global__ __launch_bounds__(256) void gather_kernel(const unsigned short* __restrict__ feat,
                                                     const int* __restrict__ rowptr,
                                                     const int* __restrict__ col,
                                                     unsigned short* __restrict__ agg, int n) {
    const int node = blockIdx.x * 8 + (threadIdx.x >> 5);
    if (node >= n) return;
    const int c4 = (threadIdx.x & 31) << 2;
    const int beg = rowptr[node];
    const int end = rowptr[node + 1];

    float4 a0 = make_float4(0.f, 0.f, 0.f, 0.f);
    float4 a1 = make_float4(0.f, 0.f, 0.f, 0.f);
    int i = beg;
    for (; i + 1 < end; i += 2) {
        int s0 = col[i], s1 = col[i + 1];
        ushort4 u0 = *(const ushort4*)&feat[(size_t)s0 * CH + c4];
        ushort4 u1 = *(const ushort4*)&feat[(size_t)s1 * CH + c4];
        a0.x += bf2f(u0.x); a0.y += bf2f(u0.y); a0.z += bf2f(u0.z); a0.w += bf2f(u0.w);
        a1.x += bf2f(u1.x); a1.y += bf2f(u1.y); a1.z += bf2f(u1.z); a1.w += bf2f(u1.w);
    }
    if (i < end) {
        int s0 = col[i];
        ushort4 u0 = *(const ushort4*)&feat[(size_t)s0 * CH + c4];
        a0.x += bf2f(u0.x); a0.y += bf2f(u0.y); a0.z += bf2f(u0.z); a0.w += bf2f(u0.w);
    }
    float inv = 1.0f / (float)max(end - beg, 1);
    ushort4 o;
    o.x = f2bf((a0.x + a1.x) * inv);
    o.y = f2bf((a0.y + a1.y) * inv);
    o.z = f2bf((a0.z + a1.z) * inv);
    o.w = f2bf((a0.w + a1.w) * inv);
    *(ushort4*)&agg[(size_t)node * CH + c4] = o;
}

// ---------------------------------------------------------------------------
// MFMA GEMM, no LDS. Block = 256 thr = 4 waves; wave = 32 rows x 128 cols
// (2 M-tiles x 8 N-tiles of 16x16, K-steps of 32 via mfma_f32_16x16x32_bf16).
// A row-major bf16 [n][128]; W pre-transposed bf16 [ncol][k].
// Fragments (guide §3): A[m=lane&15][k=quad*8+j]; B[k=quad*8+j][n=lane&15];
// C/D row=quad*4+reg, col=lane&15.
// MODE 0: Cb = bf16( relu(A1@Wl + A2@Wr + bias) )
// MODE 1: Cf = alpha*(A1@Wl + bias) + (1-alpha)*resid
template <int MODE>
__global__ __launch_bounds__(256) void mfma_gemm_kernel(
    const unsigned short* __restrict__ A1, const unsigned short* __restrict__ A2,
    const unsigned short* __restrict__ Wt1, const unsigned short* __restrict__ Wt2,
    const float* __restrict__ bias, const float* __restrict__ alpha_p,
    const float* __restrict__ resid,
    unsigned short* __restrict__ Cb, float* __restrict__ Cf, int n) {
    const int tid = threadIdx.x;
    const int wave = tid >> 6;
    const int lane = tid & 63;
    const int quad = lane >> 4;
    const int l15 = lane & 15;
    const int m0 = blockIdx.x * 128 + wave * 32;

    f32x4 acc[2][8];
#pragma unroll
    for (int t = 0; t < 2; ++t)
#pragma unroll
        for (int u = 0; u < 8; ++u) acc[t][u] = (f32x4){0.f, 0.f, 0.f, 0.f};

    const unsigned short* As[2] = {A1, A2};
    const unsigned short* Ws[2] = {Wt1, Wt2};
    const int nph = (MODE == 0) ? 2 : 1;

    for (int ph = 0; ph < nph; ++ph) {
        const unsigned short* A = As[ph];
        const unsigned short* Wt = Ws[ph];
#pragma unroll
        for (int kb = 0; kb < CH; kb += 32) {
            bf16x8 a[2], b[8];
#pragma unroll
            for (int t = 0; t < 2; ++t) {
                int row = m0 + t * 16 + l15;
                row = min(row, n - 1);                       // clamp; store guarded
                a[t] = *(const bf16x8*)&A[(size_t)row * CH + kb + quad * 8];
            }
#pragma unroll
            for (int u = 0; u < 8; ++u) {
                b[u] = *(const bf16x8*)&Wt[(size_t)(u * 16 + l15) * CH + kb + quad * 8];
            }
#pragma unroll
            for (int t = 0; t < 2; ++t)
#pragma unroll
                for (int u = 0; u < 8; ++u)
                    acc[t][u] = __builtin_amdgcn_mfma_f32_16x16x32_bf16(
                        a[t], b[u], acc[t][u], 0, 0, 0);
        }
    }

    float bv[8];
#pragma unroll
    for (int u = 0; u < 8; ++u) bv[u] = bias[u * 16 + l15];

    float al = 0.f, be = 0.f;
    if (MODE == 1) { al = alpha_p[0]; be = 1.0f - al; }

#pragma unroll
    for (int t = 0; t < 2; ++t) {
#pragma unroll
        for (int r = 0; r < 4; ++r) {
            int row = m0 + t * 16 + quad * 4 + r;
            if (row >= n) continue;
            size_t base = (size_t)row * CH;
#pragma unroll
            for (int u = 0; u < 8; ++u) {
                int colj = u * 16 + l15;
                float v = acc[t][u][r] + bv[u];
                if (MODE == 0) {
                    Cb[base + colj] = f2bf(fmaxf(v, 0.f));
                } else {
                    Cf[base + colj] = al * v + be * resid[base + colj];
                }
            }
        }
    }
}

// ---------------------------------------------------------------------------
extern "C" void kernel_launch(void* const* d_in, const int* in_sizes, int n_in,
                              void* d_out, int out_size, void* d_ws, size_t ws_size,
                              hipStream_t stream) {
    const float* x    = (const float*)d_in[0];
    const int*   ei   = (const int*)d_in[1];
    const float* W1_l = (const float*)d_in[2];
    const float* b1   = (const float*)d_in[3];
    const float* W1_r = (const float*)d_in[4];
    const float* W2_l = (const float*)d_in[5];
    const float* b2   = (const float*)d_in[6];
    const float* W2_r = (const float*)d_in[7];
    const float* Wd   = (const float*)d_in[8];
    const float* bd   = (const float*)d_in[9];
    const float* alpha = (const float*)d_in[10];
    float* out = (float*)d_out;

    const int n = in_sizes[0] / CH;
    const int E = in_sizes[1] / 2;
    const int* src = ei;
    const int* dst = ei + E;

    const size_t nCH = (size_t)n * CH;
    const int scanBlocks = (n + SCAN_B - 1) / SCAN_B;

    // workspace: bf16 features first (16B-aligned), then weights, then ints
    unsigned short* xb   = (unsigned short*)d_ws;        // [n,CH] bf16; reused as o2b
    unsigned short* hb   = xb + nCH;                     // [n,CH] bf16
    unsigned short* aggb = hb + nCH;                     // [n,CH] bf16
    unsigned short* w1lt = aggb + nCH;                   // 5 x [CH,CH] bf16 transposed
    unsigned short* w1rt = w1lt + CH * CH;
    unsigned short* w2lt = w1rt + CH * CH;
    unsigned short* w2rt = w2lt + CH * CH;
    unsigned short* wdt  = w2rt + CH * CH;
    int* cnt    = (int*)(wdt + CH * CH);                 // [n]
    int* rowptr = cnt + n;                               // [n+1]
    int* cursor = rowptr + n + 1;                        // [n]
    int* col    = cursor + n;                            // [E]
    int* bsums  = col + E;                               // [scanBlocks]
    int* boffs  = bsums + scanBlocks;                    // [scanBlocks]

    const int edgeBlocks = (E + 255) / 256;
    const int gatherBlocks = (n + 7) / 8;
    const int gemmBlocks = (n + 127) / 128;              // 391

    // ---- CSR build ----
    hipMemsetAsync(cnt, 0, (size_t)n * sizeof(int), stream);
    deg_hist_kernel<<<edgeBlocks, 256, 0, stream>>>(dst, cnt, E);
    scan_partial_kernel<<<scanBlocks, 256, 0, stream>>>(cnt, bsums, n);
    scan_blocksums_kernel<<<1, 1024, 0, stream>>>(bsums, boffs, scanBlocks);
    scan_final_kernel<<<scanBlocks, 256, 0, stream>>>(cnt, boffs, rowptr, cursor, n, E);
    fill_kernel<<<edgeBlocks, 256, 0, stream>>>(src, dst, cursor, col, E);

    // ---- dtype conversions ----
    conv_x_kernel<<<(int)(nCH / 4 + 255) / 256, 256, 0, stream>>>(x, xb, (int)(nCH / 4));
    conv_wt_kernel<<<dim3(CH * CH / 256, 5), 256, 0, stream>>>(
        W1_l, W1_r, W2_l, W2_r, Wd, w1lt, w1rt, w2lt, w2rt, wdt);

    // ---- layer 1: hb = relu(agg(xb)@W1_l + xb@W1_r + b1) ----
    gather_kernel<<<gatherBlocks, 256, 0, stream>>>(xb, rowptr, col, aggb, n);
    mfma_gemm_kernel<0><<<gemmBlocks, 256, 0, stream>>>(
        aggb, xb, w1lt, w1rt, b1, nullptr, nullptr, hb, nullptr, n);
    // ---- layer 2: o2b(=xb) = relu(agg(hb)@W2_l + hb@W2_r + b2) ----
    // xb's last reader is the layer-1 GEMM above; safe to overwrite now.
    gather_kernel<<<gatherBlocks, 256, 0, stream>>>(hb, rowptr, col, aggb, n);
    mfma_gemm_kernel<0><<<gemmBlocks, 256, 0, stream>>>(
        aggb, hb, w2lt, w2rt, b2, nullptr, nullptr, xb, nullptr, n);
    // ---- decoder + residual: out = alpha*(o2b@Wd + bd) + (1-alpha)*x ----
    mfma_gemm_kernel<1><<<gemmBlocks, 256, 0, stream>>>(
        xb, nullptr, wdt, nullptr, bd, alpha, x, nullptr, out, n);
}

// Round 7
// 275.486 us; speedup vs baseline: 3.1934x; 1.0503x over previous
//
#include <hip/hip_runtime.h>

#define CH 128
#define SCAN_B 256

typedef short bf16x8 __attribute__((ext_vector_type(8)));
typedef float f32x4 __attribute__((ext_vector_type(4)));
typedef unsigned short u16x8 __attribute__((ext_vector_type(8)));

static __device__ __forceinline__ unsigned short f2bf(float f) {
    unsigned int u = __float_as_uint(f);
    u = (u + 0x7fff + ((u >> 16) & 1)) >> 16;   // RNE
    return (unsigned short)u;
}
static __device__ __forceinline__ float bf2f(unsigned short s) {
    return __uint_as_float(((unsigned int)s) << 16);
}

// ---------------------------------------------------------------------------
// Fused prep: [0, xBlocks)           : fp32->bf16 feature conversion
//             [xBlocks, xBlocks+320) : 5 weight matrices -> bf16 transposed
//             [.., +edgeBlocks)      : dst-degree histogram
__global__ __launch_bounds__(256) void prep_kernel(
    const float* __restrict__ x, unsigned short* __restrict__ xb, int total4,
    const float* __restrict__ w0, const float* __restrict__ w1,
    const float* __restrict__ w2, const float* __restrict__ w3,
    const float* __restrict__ w4,
    unsigned short* __restrict__ t0, unsigned short* __restrict__ t1,
    unsigned short* __restrict__ t2, unsigned short* __restrict__ t3,
    unsigned short* __restrict__ t4,
    const int* __restrict__ dst, int* __restrict__ cnt, int E,
    int xBlocks, int wBlocks) {
    int b = blockIdx.x;
    if (b < xBlocks) {
        int idx = b * 256 + threadIdx.x;
        if (idx < total4) {
            float4 v = ((const float4*)x)[idx];
            ushort4 o;
            o.x = f2bf(v.x); o.y = f2bf(v.y); o.z = f2bf(v.z); o.w = f2bf(v.w);
            ((ushort4*)xb)[idx] = o;
        }
    } else if (b < xBlocks + wBlocks) {
        int idx = (b - xBlocks) * 256 + threadIdx.x;   // 0..81919
        int wsel = idx >> 14;                          // 16384 elems per matrix
        int r = idx & 16383;
        const float* W; unsigned short* T;
        switch (wsel) {
            case 0: W = w0; T = t0; break;
            case 1: W = w1; T = t1; break;
            case 2: W = w2; T = t2; break;
            case 3: W = w3; T = t3; break;
            default: W = w4; T = t4; break;
        }
        int k = r >> 7, nn = r & 127;
        T[nn * CH + k] = f2bf(W[r]);
    } else {
        int e = (b - xBlocks - wBlocks) * 256 + threadIdx.x;
        if (e < E) atomicAdd(&cnt[dst[e]], 1);
    }
}

// ---------------------------------------------------------------------------
__global__ __launch_bounds__(256) void scan_partial_kernel(const int* __restrict__ cnt,
                                                           int* __restrict__ blockSums,
                                                           int n) {
    __shared__ int red[256];
    const int tid = threadIdx.x;
    const int i = blockIdx.x * SCAN_B + tid;
    red[tid] = (i < n) ? cnt[i] : 0;
    __syncthreads();
#pragma unroll
    for (int off = 128; off > 0; off >>= 1) {
        if (tid < off) red[tid] += red[tid + off];
        __syncthreads();
    }
    if (tid == 0) blockSums[blockIdx.x] = red[0];
}

__global__ __launch_bounds__(1024) void scan_blocksums_kernel(const int* __restrict__ blockSums,
                                                              int* __restrict__ blockOffsets,
                                                              int B) {
    __shared__ int s[1024];
    const int tid = threadIdx.x;
    int v = (tid < B) ? blockSums[tid] : 0;
    s[tid] = v;
    __syncthreads();
    for (int off = 1; off < 1024; off <<= 1) {
        int t = (tid >= off) ? s[tid - off] : 0;
        __syncthreads();
        s[tid] += t;
        __syncthreads();
    }
    if (tid < B) blockOffsets[tid] = s[tid] - v;
}

__global__ __launch_bounds__(256) void scan_final_kernel(const int* __restrict__ cnt,
                                                         const int* __restrict__ blockOffsets,
                                                         int* __restrict__ rowptr,
                                                         int* __restrict__ cursor,
                                                         int n, int E) {
    __shared__ int s[256];
    const int tid = threadIdx.x;
    const int i = blockIdx.x * SCAN_B + tid;
    int v = (i < n) ? cnt[i] : 0;
    s[tid] = v;
    __syncthreads();
    for (int off = 1; off < 256; off <<= 1) {
        int t = (tid >= off) ? s[tid - off] : 0;
        __syncthreads();
        s[tid] += t;
        __syncthreads();
    }
    if (i < n) {
        int ex = blockOffsets[blockIdx.x] + s[tid] - v;
        rowptr[i] = ex;
        cursor[i] = ex;
    }
    if (blockIdx.x == 0 && tid == 0) rowptr[n] = E;
}

__global__ __launch_bounds__(256) void fill_kernel(const int* __restrict__ src,
                                                   const int* __restrict__ dst,
                                                   int* __restrict__ cursor,
                                                   int* __restrict__ col, int E) {
    int e = blockIdx.x * 256 + threadIdx.x;
    if (e < E) {
        int pos = atomicAdd(&cursor[dst[e]], 1);
        col[pos] = src[e];
    }
}

// ---------------------------------------------------------------------------
// Gather v2: 16 lanes/node, lane owns 8 channels (ushort8 = 16B load/neighbor),
// 16 nodes per 256-block, neighbor loop unrolled 4x for MLP.
__global__ __launch_bounds__(256) void gather_kernel(const unsigned short* __restrict__ feat,
                                                     const int* __restrict__ rowptr,
                                                     const int* __restrict__ col,
                                                     unsigned short* __restrict__ agg, int n) {
    const int node = blockIdx.x * 16 + (threadIdx.x >> 4);
    if (node >= n) return;
    const int c8 = (threadIdx.x & 15) << 3;
    const int beg = rowptr[node];
    const int end = rowptr[node + 1];

    float acc[8];
#pragma unroll
    for (int j = 0; j < 8; ++j) acc[j] = 0.f;

    int i = beg;
    for (; i + 3 < end; i += 4) {
        int s0 = col[i], s1 = col[i + 1], s2 = col[i + 2], s3 = col[i + 3];
        u16x8 v0 = *(const u16x8*)&feat[(size_t)s0 * CH + c8];
        u16x8 v1 = *(const u16x8*)&feat[(size_t)s1 * CH + c8];
        u16x8 v2 = *(const u16x8*)&feat[(size_t)s2 * CH + c8];
        u16x8 v3 = *(const u16x8*)&feat[(size_t)s3 * CH + c8];
#pragma unroll
        for (int j = 0; j < 8; ++j)
            acc[j] += bf2f(v0[j]) + bf2f(v1[j]) + bf2f(v2[j]) + bf2f(v3[j]);
    }
    for (; i < end; ++i) {
        u16x8 v0 = *(const u16x8*)&feat[(size_t)col[i] * CH + c8];
#pragma unroll
        for (int j = 0; j < 8; ++j) acc[j] += bf2f(v0[j]);
    }

    float inv = 1.0f / (float)max(end - beg, 1);
    u16x8 o;
#pragma unroll
    for (int j = 0; j < 8; ++j) o[j] = f2bf(acc[j] * inv);
    *(u16x8*)&agg[(size_t)node * CH + c8] = o;
}

// ---------------------------------------------------------------------------
// MFMA GEMM, no LDS. Block = 256 thr = 4 waves; wave = 32 rows x 128 cols.
// A row-major bf16 [n][128]; W pre-transposed bf16 [ncol][k].
// MODE 0: Cb = bf16( relu(A1@Wl + A2@Wr + bias) )
// MODE 1: Cf = alpha*(A1@Wl + bias) + (1-alpha)*resid
template <int MODE>
__global__ __launch_bounds__(256) void mfma_gemm_kernel(
    const unsigned short* __restrict__ A1, const unsigned short* __restrict__ A2,
    const unsigned short* __restrict__ Wt1, const unsigned short* __restrict__ Wt2,
    const float* __restrict__ bias, const float* __restrict__ alpha_p,
    const float* __restrict__ resid,
    unsigned short* __restrict__ Cb, float* __restrict__ Cf, int n) {
    const int tid = threadIdx.x;
    const int wave = tid >> 6;
    const int lane = tid & 63;
    const int quad = lane >> 4;
    const int l15 = lane & 15;
    const int m0 = blockIdx.x * 128 + wave * 32;

    f32x4 acc[2][8];
#pragma unroll
    for (int t = 0; t < 2; ++t)
#pragma unroll
        for (int u = 0; u < 8; ++u) acc[t][u] = (f32x4){0.f, 0.f, 0.f, 0.f};

    const unsigned short* As[2] = {A1, A2};
    const unsigned short* Ws[2] = {Wt1, Wt2};
    const int nph = (MODE == 0) ? 2 : 1;

    for (int ph = 0; ph < nph; ++ph) {
        const unsigned short* A = As[ph];
        const unsigned short* Wt = Ws[ph];
#pragma unroll
        for (int kb = 0; kb < CH; kb += 32) {
            bf16x8 a[2], b[8];
#pragma unroll
            for (int t = 0; t < 2; ++t) {
                int row = m0 + t * 16 + l15;
                row = min(row, n - 1);                       // clamp; store guarded
                a[t] = *(const bf16x8*)&A[(size_t)row * CH + kb + quad * 8];
            }
#pragma unroll
            for (int u = 0; u < 8; ++u) {
                b[u] = *(const bf16x8*)&Wt[(size_t)(u * 16 + l15) * CH + kb + quad * 8];
            }
#pragma unroll
            for (int t = 0; t < 2; ++t)
#pragma unroll
                for (int u = 0; u < 8; ++u)
                    acc[t][u] = __builtin_amdgcn_mfma_f32_16x16x32_bf16(
                        a[t], b[u], acc[t][u], 0, 0, 0);
        }
    }

    float bv[8];
#pragma unroll
    for (int u = 0; u < 8; ++u) bv[u] = bias[u * 16 + l15];

    float al = 0.f, be = 0.f;
    if (MODE == 1) { al = alpha_p[0]; be = 1.0f - al; }

#pragma unroll
    for (int t = 0; t < 2; ++t) {
#pragma unroll
        for (int r = 0; r < 4; ++r) {
            int row = m0 + t * 16 + quad * 4 + r;
            if (row >= n) continue;
            size_t base = (size_t)row * CH;
#pragma unroll
            for (int u = 0; u < 8; ++u) {
                int colj = u * 16 + l15;
                float v = acc[t][u][r] + bv[u];
                if (MODE == 0) {
                    Cb[base + colj] = f2bf(fmaxf(v, 0.f));
                } else {
                    Cf[base + colj] = al * v + be * resid[base + colj];
                }
            }
        }
    }
}

// ---------------------------------------------------------------------------
extern "C" void kernel_launch(void* const* d_in, const int* in_sizes, int n_in,
                              void* d_out, int out_size, void* d_ws, size_t ws_size,
                              hipStream_t stream) {
    const float* x    = (const float*)d_in[0];
    const int*   ei   = (const int*)d_in[1];
    const float* W1_l = (const float*)d_in[2];
    const float* b1   = (const float*)d_in[3];
    const float* W1_r = (const float*)d_in[4];
    const float* W2_l = (const float*)d_in[5];
    const float* b2   = (const float*)d_in[6];
    const float* W2_r = (const float*)d_in[7];
    const float* Wd   = (const float*)d_in[8];
    const float* bd   = (const float*)d_in[9];
    const float* alpha = (const float*)d_in[10];
    float* out = (float*)d_out;

    const int n = in_sizes[0] / CH;
    const int E = in_sizes[1] / 2;
    const int* src = ei;
    const int* dst = ei + E;

    const size_t nCH = (size_t)n * CH;
    const int scanBlocks = (n + SCAN_B - 1) / SCAN_B;

    unsigned short* xb   = (unsigned short*)d_ws;        // [n,CH] bf16; reused as o2b
    unsigned short* hb   = xb + nCH;                     // [n,CH] bf16
    unsigned short* aggb = hb + nCH;                     // [n,CH] bf16
    unsigned short* w1lt = aggb + nCH;                   // 5 x [CH,CH] bf16 transposed
    unsigned short* w1rt = w1lt + CH * CH;
    unsigned short* w2lt = w1rt + CH * CH;
    unsigned short* w2rt = w2lt + CH * CH;
    unsigned short* wdt  = w2rt + CH * CH;
    int* cnt    = (int*)(wdt + CH * CH);                 // [n]
    int* rowptr = cnt + n;                               // [n+1]
    int* cursor = rowptr + n + 1;                        // [n]
    int* col    = cursor + n;                            // [E]
    int* bsums  = col + E;                               // [scanBlocks]
    int* boffs  = bsums + scanBlocks;                    // [scanBlocks]

    const int edgeBlocks = (E + 255) / 256;              // 2500
    const int xBlocks = (int)((nCH / 4 + 255) / 256);    // 6250
    const int wBlocks = 5 * CH * CH / 256;               // 320
    const int gatherBlocks = (n + 15) / 16;              // 3125
    const int gemmBlocks = (n + 127) / 128;              // 391

    // ---- fused prep (conv_x + conv_wt + deg-hist) ----
    hipMemsetAsync(cnt, 0, (size_t)n * sizeof(int), stream);
    prep_kernel<<<xBlocks + wBlocks + edgeBlocks, 256, 0, stream>>>(
        x, xb, (int)(nCH / 4),
        W1_l, W1_r, W2_l, W2_r, Wd, w1lt, w1rt, w2lt, w2rt, wdt,
        dst, cnt, E, xBlocks, wBlocks);
    // ---- scan + bucket ----
    scan_partial_kernel<<<scanBlocks, 256, 0, stream>>>(cnt, bsums, n);
    scan_blocksums_kernel<<<1, 1024, 0, stream>>>(bsums, boffs, scanBlocks);
    scan_final_kernel<<<scanBlocks, 256, 0, stream>>>(cnt, boffs, rowptr, cursor, n, E);
    fill_kernel<<<edgeBlocks, 256, 0, stream>>>(src, dst, cursor, col, E);

    // ---- layer 1: hb = relu(agg(xb)@W1_l + xb@W1_r + b1) ----
    gather_kernel<<<gatherBlocks, 256, 0, stream>>>(xb, rowptr, col, aggb, n);
    mfma_gemm_kernel<0><<<gemmBlocks, 256, 0, stream>>>(
        aggb, xb, w1lt, w1rt, b1, nullptr, nullptr, hb, nullptr, n);
    // ---- layer 2: o2b(=xb) = relu(agg(hb)@W2_l + hb@W2_r + b2) ----
    gather_kernel<<<gatherBlocks, 256, 0, stream>>>(hb, rowptr, col, aggb, n);
    mfma_gemm_kernel<0><<<gemmBlocks, 256, 0, stream>>>(
        aggb, hb, w2lt, w2rt, b2, nullptr, nullptr, xb, nullptr, n);
    // ---- decoder + residual: out = alpha*(o2b@Wd + bd) + (1-alpha)*x ----
    mfma_gemm_kernel<1><<<gemmBlocks, 256, 0, stream>>>(
        xb, nullptr, wdt, nullptr, bd, alpha, x, nullptr, out, n);
}

// Round 8
// 274.587 us; speedup vs baseline: 3.2039x; 1.0033x over previous
//
#include <hip/hip_runtime.h>

#define CH 128
#define SCAN_B 256

typedef short bf16x8 __attribute__((ext_vector_type(8)));
typedef float f32x4 __attribute__((ext_vector_type(4)));
typedef unsigned short u16x8 __attribute__((ext_vector_type(8)));

static __device__ __forceinline__ unsigned short f2bf(float f) {
    unsigned int u = __float_as_uint(f);
    u = (u + 0x7fff + ((u >> 16) & 1)) >> 16;   // RNE
    return (unsigned short)u;
}
static __device__ __forceinline__ float bf2f(unsigned short s) {
    return __uint_as_float(((unsigned int)s) << 16);
}

// ---------------------------------------------------------------------------
// Fused prep: [0, xBlocks)           : fp32->bf16 feature conversion
//             [xBlocks, +wBlocks)    : 5 weight matrices -> bf16 transposed
//             [.., +edgeBlocks)      : dst-degree histogram
__global__ __launch_bounds__(256) void prep_kernel(
    const float* __restrict__ x, unsigned short* __restrict__ xb, int total4,
    const float* __restrict__ w0, const float* __restrict__ w1,
    const float* __restrict__ w2, const float* __restrict__ w3,
    const float* __restrict__ w4,
    unsigned short* __restrict__ t0, unsigned short* __restrict__ t1,
    unsigned short* __restrict__ t2, unsigned short* __restrict__ t3,
    unsigned short* __restrict__ t4,
    const int* __restrict__ dst, int* __restrict__ cnt, int E,
    int xBlocks, int wBlocks) {
    int b = blockIdx.x;
    if (b < xBlocks) {
        int idx = b * 256 + threadIdx.x;
        if (idx < total4) {
            float4 v = ((const float4*)x)[idx];
            ushort4 o;
            o.x = f2bf(v.x); o.y = f2bf(v.y); o.z = f2bf(v.z); o.w = f2bf(v.w);
            ((ushort4*)xb)[idx] = o;
        }
    } else if (b < xBlocks + wBlocks) {
        int idx = (b - xBlocks) * 256 + threadIdx.x;   // 0..81919
        int wsel = idx >> 14;                          // 16384 elems per matrix
        int r = idx & 16383;
        const float* W; unsigned short* T;
        switch (wsel) {
            case 0: W = w0; T = t0; break;
            case 1: W = w1; T = t1; break;
            case 2: W = w2; T = t2; break;
            case 3: W = w3; T = t3; break;
            default: W = w4; T = t4; break;
        }
        int k = r >> 7, nn = r & 127;
        T[nn * CH + k] = f2bf(W[r]);
    } else {
        int e = (b - xBlocks - wBlocks) * 256 + threadIdx.x;
        if (e < E) atomicAdd(&cnt[dst[e]], 1);
    }
}

// ---------------------------------------------------------------------------
// Scan phase 1: per-block sums of cnt chunks
__global__ __launch_bounds__(256) void scan_partial_kernel(const int* __restrict__ cnt,
                                                           int* __restrict__ blockSums,
                                                           int n) {
    __shared__ int red[256];
    const int tid = threadIdx.x;
    const int i = blockIdx.x * SCAN_B + tid;
    red[tid] = (i < n) ? cnt[i] : 0;
    __syncthreads();
#pragma unroll
    for (int off = 128; off > 0; off >>= 1) {
        if (tid < off) red[tid] += red[tid + off];
        __syncthreads();
    }
    if (tid == 0) blockSums[blockIdx.x] = red[0];
}

// Scan phase 2 (fused): block b sums predecessors' partials in LDS, then does
// its local 256-chunk exclusive scan. Requires scanBlocks <= 256.
__global__ __launch_bounds__(256) void scan_final_kernel(const int* __restrict__ cnt,
                                                         const int* __restrict__ blockSums,
                                                         int* __restrict__ rowptr,
                                                         int* __restrict__ cursor,
                                                         int n, int E) {
    __shared__ int s[256];
    __shared__ int blkoff;
    const int tid = threadIdx.x;

    // reduce predecessors' sums
    s[tid] = (tid < (int)blockIdx.x) ? blockSums[tid] : 0;
    __syncthreads();
#pragma unroll
    for (int off = 128; off > 0; off >>= 1) {
        if (tid < off) s[tid] += s[tid + off];
        __syncthreads();
    }
    if (tid == 0) blkoff = s[0];
    __syncthreads();

    // local exclusive scan
    const int i = blockIdx.x * SCAN_B + tid;
    int v = (i < n) ? cnt[i] : 0;
    s[tid] = v;
    __syncthreads();
    for (int off = 1; off < 256; off <<= 1) {
        int t = (tid >= off) ? s[tid - off] : 0;
        __syncthreads();
        s[tid] += t;
        __syncthreads();
    }
    if (i < n) {
        int ex = blkoff + s[tid] - v;
        rowptr[i] = ex;
        cursor[i] = ex;
    }
    if (blockIdx.x == 0 && tid == 0) rowptr[n] = E;
}

__global__ __launch_bounds__(256) void fill_kernel(const int* __restrict__ src,
                                                   const int* __restrict__ dst,
                                                   int* __restrict__ cursor,
                                                   int* __restrict__ col, int E) {
    int e = blockIdx.x * 256 + threadIdx.x;
    if (e < E) {
        int pos = atomicAdd(&cursor[dst[e]], 1);
        col[pos] = src[e];
    }
}

// ---------------------------------------------------------------------------
// Gather v3: 16 lanes/node (ushort8 = 16B/lane/neighbor), 16 nodes/block,
// neighbor loop unrolled 8x for deeper MLP.
__global__ __launch_bounds__(256) void gather_kernel(const unsigned short* __restrict__ feat,
                                                     const int* __restrict__ rowptr,
                                                     const int* __restrict__ col,
                                                     unsigned short* __restrict__ agg, int n) {
    const int node = blockIdx.x * 16 + (threadIdx.x >> 4);
    if (node >= n) return;
    const int c8 = (threadIdx.x & 15) << 3;
    const int beg = rowptr[node];
    const int end = rowptr[node + 1];

    float acc[8];
#pragma unroll
    for (int j = 0; j < 8; ++j) acc[j] = 0.f;

    int i = beg;
    for (; i + 7 < end; i += 8) {
        int s0 = col[i],     s1 = col[i + 1], s2 = col[i + 2], s3 = col[i + 3];
        int s4 = col[i + 4], s5 = col[i + 5], s6 = col[i + 6], s7 = col[i + 7];
        u16x8 v0 = *(const u16x8*)&feat[(size_t)s0 * CH + c8];
        u16x8 v1 = *(const u16x8*)&feat[(size_t)s1 * CH + c8];
        u16x8 v2 = *(const u16x8*)&feat[(size_t)s2 * CH + c8];
        u16x8 v3 = *(const u16x8*)&feat[(size_t)s3 * CH + c8];
        u16x8 v4 = *(const u16x8*)&feat[(size_t)s4 * CH + c8];
        u16x8 v5 = *(const u16x8*)&feat[(size_t)s5 * CH + c8];
        u16x8 v6 = *(const u16x8*)&feat[(size_t)s6 * CH + c8];
        u16x8 v7 = *(const u16x8*)&feat[(size_t)s7 * CH + c8];
#pragma unroll
        for (int j = 0; j < 8; ++j)
            acc[j] += ((bf2f(v0[j]) + bf2f(v1[j])) + (bf2f(v2[j]) + bf2f(v3[j]))) +
                      ((bf2f(v4[j]) + bf2f(v5[j])) + (bf2f(v6[j]) + bf2f(v7[j])));
    }
    for (; i + 1 < end; i += 2) {
        int s0 = col[i], s1 = col[i + 1];
        u16x8 v0 = *(const u16x8*)&feat[(size_t)s0 * CH + c8];
        u16x8 v1 = *(const u16x8*)&feat[(size_t)s1 * CH + c8];
#pragma unroll
        for (int j = 0; j < 8; ++j) acc[j] += bf2f(v0[j]) + bf2f(v1[j]);
    }
    if (i < end) {
        u16x8 v0 = *(const u16x8*)&feat[(size_t)col[i] * CH + c8];
#pragma unroll
        for (int j = 0; j < 8; ++j) acc[j] += bf2f(v0[j]);
    }

    float inv = 1.0f / (float)max(end - beg, 1);
    u16x8 o;
#pragma unroll
    for (int j = 0; j < 8; ++j) o[j] = f2bf(acc[j] * inv);
    *(u16x8*)&agg[(size_t)node * CH + c8] = o;
}

// ---------------------------------------------------------------------------
// MFMA GEMM, no LDS. Block = 256 thr = 4 waves; wave = 32 rows x 128 cols.
// A row-major bf16 [n][128]; W pre-transposed bf16 [ncol][k].
// MODE 0: Cb = bf16( relu(A1@Wl + A2@Wr + bias) )
// MODE 1: Cf = alpha*(A1@Wl + bias) + (1-alpha)*bf2f(residb)
template <int MODE>
__global__ __launch_bounds__(256) void mfma_gemm_kernel(
    const unsigned short* __restrict__ A1, const unsigned short* __restrict__ A2,
    const unsigned short* __restrict__ Wt1, const unsigned short* __restrict__ Wt2,
    const float* __restrict__ bias, const float* __restrict__ alpha_p,
    const unsigned short* __restrict__ residb,
    unsigned short* __restrict__ Cb, float* __restrict__ Cf, int n) {
    const int tid = threadIdx.x;
    const int wave = tid >> 6;
    const int lane = tid & 63;
    const int quad = lane >> 4;
    const int l15 = lane & 15;
    const int m0 = blockIdx.x * 128 + wave * 32;

    f32x4 acc[2][8];
#pragma unroll
    for (int t = 0; t < 2; ++t)
#pragma unroll
        for (int u = 0; u < 8; ++u) acc[t][u] = (f32x4){0.f, 0.f, 0.f, 0.f};

    const unsigned short* As[2] = {A1, A2};
    const unsigned short* Ws[2] = {Wt1, Wt2};
    const int nph = (MODE == 0) ? 2 : 1;

    for (int ph = 0; ph < nph; ++ph) {
        const unsigned short* A = As[ph];
        const unsigned short* Wt = Ws[ph];
#pragma unroll
        for (int kb = 0; kb < CH; kb += 32) {
            bf16x8 a[2], b[8];
#pragma unroll
            for (int t = 0; t < 2; ++t) {
                int row = m0 + t * 16 + l15;
                row = min(row, n - 1);                       // clamp; store guarded
                a[t] = *(const bf16x8*)&A[(size_t)row * CH + kb + quad * 8];
            }
#pragma unroll
            for (int u = 0; u < 8; ++u) {
                b[u] = *(const bf16x8*)&Wt[(size_t)(u * 16 + l15) * CH + kb + quad * 8];
            }
#pragma unroll
            for (int t = 0; t < 2; ++t)
#pragma unroll
                for (int u = 0; u < 8; ++u)
                    acc[t][u] = __builtin_amdgcn_mfma_f32_16x16x32_bf16(
                        a[t], b[u], acc[t][u], 0, 0, 0);
        }
    }

    float bv[8];
#pragma unroll
    for (int u = 0; u < 8; ++u) bv[u] = bias[u * 16 + l15];

    float al = 0.f, be = 0.f;
    if (MODE == 1) { al = alpha_p[0]; be = 1.0f - al; }

#pragma unroll
    for (int t = 0; t < 2; ++t) {
#pragma unroll
        for (int r = 0; r < 4; ++r) {
            int row = m0 + t * 16 + quad * 4 + r;
            if (row >= n) continue;
            size_t base = (size_t)row * CH;
#pragma unroll
            for (int u = 0; u < 8; ++u) {
                int colj = u * 16 + l15;
                float v = acc[t][u][r] + bv[u];
                if (MODE == 0) {
                    Cb[base + colj] = f2bf(fmaxf(v, 0.f));
                } else {
                    Cf[base + colj] = al * v + be * bf2f(residb[base + colj]);
                }
            }
        }
    }
}

// ---------------------------------------------------------------------------
extern "C" void kernel_launch(void* const* d_in, const int* in_sizes, int n_in,
                              void* d_out, int out_size, void* d_ws, size_t ws_size,
                              hipStream_t stream) {
    const float* x    = (const float*)d_in[0];
    const int*   ei   = (const int*)d_in[1];
    const float* W1_l = (const float*)d_in[2];
    const float* b1   = (const float*)d_in[3];
    const float* W1_r = (const float*)d_in[4];
    const float* W2_l = (const float*)d_in[5];
    const float* b2   = (const float*)d_in[6];
    const float* W2_r = (const float*)d_in[7];
    const float* Wd   = (const float*)d_in[8];
    const float* bd   = (const float*)d_in[9];
    const float* alpha = (const float*)d_in[10];
    float* out = (float*)d_out;

    const int n = in_sizes[0] / CH;
    const int E = in_sizes[1] / 2;
    const int* src = ei;
    const int* dst = ei + E;

    const size_t nCH = (size_t)n * CH;
    const int scanBlocks = (n + SCAN_B - 1) / SCAN_B;    // 196 (must be <= 256)

    unsigned short* xb   = (unsigned short*)d_ws;        // [n,CH] bf16 (kept pristine)
    unsigned short* hb   = xb + nCH;                     // [n,CH] bf16
    unsigned short* aggb = hb + nCH;                     // [n,CH] bf16
    unsigned short* ob   = aggb + nCH;                   // [n,CH] bf16 (layer-2 out)
    unsigned short* w1lt = ob + nCH;                     // 5 x [CH,CH] bf16 transposed
    unsigned short* w1rt = w1lt + CH * CH;
    unsigned short* w2lt = w1rt + CH * CH;
    unsigned short* w2rt = w2lt + CH * CH;
    unsigned short* wdt  = w2rt + CH * CH;
    int* cnt    = (int*)(wdt + CH * CH);                 // [n]
    int* rowptr = cnt + n;                               // [n+1]
    int* cursor = rowptr + n + 1;                        // [n]
    int* col    = cursor + n;                            // [E]
    int* bsums  = col + E;                               // [scanBlocks]

    const int edgeBlocks = (E + 255) / 256;              // 2500
    const int xBlocks = (int)((nCH / 4 + 255) / 256);    // 6250
    const int wBlocks = 5 * CH * CH / 256;               // 320
    const int gatherBlocks = (n + 15) / 16;              // 3125
    const int gemmBlocks = (n + 127) / 128;              // 391

    // ---- fused prep (conv_x + conv_wt + deg-hist) ----
    hipMemsetAsync(cnt, 0, (size_t)n * sizeof(int), stream);
    prep_kernel<<<xBlocks + wBlocks + edgeBlocks, 256, 0, stream>>>(
        x, xb, (int)(nCH / 4),
        W1_l, W1_r, W2_l, W2_r, Wd, w1lt, w1rt, w2lt, w2rt, wdt,
        dst, cnt, E, xBlocks, wBlocks);
    // ---- scan (2 kernels) + bucket ----
    scan_partial_kernel<<<scanBlocks, 256, 0, stream>>>(cnt, bsums, n);
    scan_final_kernel<<<scanBlocks, 256, 0, stream>>>(cnt, bsums, rowptr, cursor, n, E);
    fill_kernel<<<edgeBlocks, 256, 0, stream>>>(src, dst, cursor, col, E);

    // ---- layer 1: hb = relu(agg(xb)@W1_l + xb@W1_r + b1) ----
    gather_kernel<<<gatherBlocks, 256, 0, stream>>>(xb, rowptr, col, aggb, n);
    mfma_gemm_kernel<0><<<gemmBlocks, 256, 0, stream>>>(
        aggb, xb, w1lt, w1rt, b1, nullptr, nullptr, hb, nullptr, n);
    // ---- layer 2: ob = relu(agg(hb)@W2_l + hb@W2_r + b2) ----
    gather_kernel<<<gatherBlocks, 256, 0, stream>>>(hb, rowptr, col, aggb, n);
    mfma_gemm_kernel<0><<<gemmBlocks, 256, 0, stream>>>(
        aggb, hb, w2lt, w2rt, b2, nullptr, nullptr, ob, nullptr, n);
    // ---- decoder + residual: out = alpha*(ob@Wd + bd) + (1-alpha)*xb ----
    mfma_gemm_kernel<1><<<gemmBlocks, 256, 0, stream>>>(
        ob, nullptr, wdt, nullptr, bd, alpha, xb, nullptr, out, n);
}